// Round 2
// baseline (345.832 us; speedup 1.0000x reference)
//
#include <hip/hip_runtime.h>
#include <math.h>

// Gaussian blur, (64, 512, 512, 3) f32 NHWC, per-batch sigma.
// Reference's kernel k[b,di,dj] depends only on dj (xs broadcast in ref),
// so conv = vertical 3-row UNWEIGHTED sum (x 1/3), then horizontal
// [w0, w1, w0] over pixels (stride 3 floats, channel-interleaved).
//   s = 3*stds[b]; e = exp(-1/s^2); w1 = 1/(3(1+2e)); w0 = e*w1
//
// Single-pass, 1x-read design: each WAVE owns a 64-float4-wide column strip
// (256 floats) and walks down RS rows with a rolling 3-row register window.
// Horizontal colsum neighbors via shuffles; wave-edge lanes keep a rolling
// halo column (predicated extra load on lanes 0/63 only). No LDS, no barriers.

constexpr int Wd   = 512;
constexpr int Hd   = 512;
constexpr int Cd   = 3;
constexpr int ROWF = Wd * Cd;        // 1536 floats per row
constexpr int SEGS = ROWF / (64*4);  // 6 wave-segments across a row
constexpr int RS   = 32;             // rows per strip
constexpr int NSTR = Hd / RS;        // 16 strips
constexpr int TPB  = 256;            // 4 waves per block

__device__ __forceinline__ float4 f4zero() { return make_float4(0.f,0.f,0.f,0.f); }
__device__ __forceinline__ float4 f4add3(float4 a, float4 b, float4 c) {
    return make_float4(a.x+b.x+c.x, a.y+b.y+c.y, a.z+b.z+c.z, a.w+b.w+c.w);
}

__global__ __launch_bounds__(TPB) void gauss_strip_kernel(
    const float* __restrict__ x,
    const float* __restrict__ stds,
    float* __restrict__ out)
{
    const int lane = threadIdx.x & 63;
    const int w    = blockIdx.x * (TPB/64) + (threadIdx.x >> 6);  // global wave id
    const int strip = w & (NSTR - 1);
    const int seg   = (w >> 4) % SEGS;
    const int b     = w / (NSTR * SEGS);

    const float s  = stds[b] * 3.0f;
    const float e  = expf(-1.0f / (s * s));
    const float w1 = 1.0f / (3.0f * (1.0f + 2.0f * e));
    const float w0 = e * w1;

    const int f4 = seg * 64 + lane;              // float4 index within row
    const size_t imgoff = (size_t)b * Hd * ROWF + (size_t)f4 * 4;
    const float* cb  = x   + imgoff;             // column base (row 0)
    float*       cbo = out + imgoff;

    const bool haloL = (lane == 0)  && (seg > 0);
    const bool haloR = (lane == 63) && (seg < SEGS - 1);
    const bool halo  = haloL || haloR;
    const int  hoff  = haloL ? -4 : 4;           // float offset of halo float4

    const int r0 = strip * RS;

    // rolling window registers
    float4 rprev = f4zero(), rcur, hprev = f4zero(), hcur = f4zero();

    if (r0 > 0) {
        rprev = *(const float4*)(cb + (size_t)(r0-1) * ROWF);
        if (halo) hprev = *(const float4*)(cb + (size_t)(r0-1) * ROWF + hoff);
    }
    rcur = *(const float4*)(cb + (size_t)r0 * ROWF);
    if (halo) hcur = *(const float4*)(cb + (size_t)r0 * ROWF + hoff);

    #pragma unroll 4
    for (int k = 0; k < RS; ++k) {
        const int r = r0 + k;
        float4 rnext = f4zero(), hnext = f4zero();
        if (r + 1 < Hd) {                         // wave-uniform
            rnext = *(const float4*)(cb + (size_t)(r+1) * ROWF);
            if (halo) hnext = *(const float4*)(cb + (size_t)(r+1) * ROWF + hoff);
        }

        const float4 m  = f4add3(rprev, rcur, rnext);   // colsum for own float4
        const float4 mh = f4add3(hprev, hcur, hnext);   // colsum for halo float4

        // neighbor colsums: p = cs[f-4..f-1] (lane-1's m), n = cs[f+4..f+7]
        float py = __shfl_up(m.y, 1);
        float pz = __shfl_up(m.z, 1);
        float pw = __shfl_up(m.w, 1);
        float nx = __shfl_down(m.x, 1);
        float ny = __shfl_down(m.y, 1);
        float nz = __shfl_down(m.z, 1);
        if (lane == 0)  { py = mh.y; pz = mh.z; pw = mh.w; }  // mh=0 at image edge
        if (lane == 63) { nx = mh.x; ny = mh.y; nz = mh.z; }

        float4 o;
        o.x = w1 * m.x + w0 * (py  + m.w);
        o.y = w1 * m.y + w0 * (pz  + nx);
        o.z = w1 * m.z + w0 * (pw  + ny);
        o.w = w1 * m.w + w0 * (m.x + nz);

        *(float4*)(cbo + (size_t)r * ROWF) = o;

        rprev = rcur; rcur = rnext;
        hprev = hcur; hcur = hnext;
    }
}

extern "C" void kernel_launch(void* const* d_in, const int* in_sizes, int n_in,
                              void* d_out, int out_size, void* d_ws, size_t ws_size,
                              hipStream_t stream) {
    const float* x    = (const float*)d_in[0];
    const float* stds = (const float*)d_in[1];
    float* out        = (float*)d_out;

    const int nwaves  = 64 * SEGS * NSTR;        // 6144 waves
    const int nblocks = nwaves / (TPB / 64);     // 1536 blocks
    gauss_strip_kernel<<<nblocks, TPB, 0, stream>>>(x, stds, out);
}